// Round 7
// baseline (76.968 us; speedup 1.0000x reference)
//
#include <hip/hip_runtime.h>

#define Zdim 128
#define Ydim 512
#define Xdim 512
#define Pdim 15
#define NWt  19

typedef __attribute__((ext_vector_type(4))) float f4;
struct F4 { float v[4]; };

__device__ __forceinline__ F4 ld4(const float* p) {
    f4 t = *(const f4*)p;
    F4 r; r.v[0] = t[0]; r.v[1] = t[1]; r.v[2] = t[2]; r.v[3] = t[3];
    return r;
}

// One thread per 4 consecutive x; marches ALL 128 z-planes (no z-chunking ->
// zero history-preload traffic; HBM reads = exactly the compulsory 134 MB).
// - 15-deep register history ring, fully static (main loop 120 iters under
//   unroll 15; the 6 pipeline remainder iters + 2 tail STEPs are written out
//   with constant buffer indices so nothing is dynamically indexed)
// - weights via wave-uniform global reads -> s_load into SGPRs (no LDS)
// - west/nw via __shfl_up of lane-1's vectors; lane 0 keeps 1-lane masked loads
// - distance-2 prefetch (3 rotating buffers), nontemporal f4 stores
// - XCD-aware remap: bid%8 == XCD; each XCD owns 64 consecutive y rows so
//   north-halo reads hit the local L2
__global__ __launch_bounds__(256, 1) void spec_pred_kernel(
    const float* __restrict__ img,
    const float* __restrict__ wts,
    float* __restrict__ out)
{
    const int bid = blockIdx.x;                        // 0..255
    const int yb  = ((bid & 7) << 5) | (bid >> 3);     // XCD-contiguous y-pair
    const int id  = (yb << 8) | threadIdx.x;           // 0..65535
    const int xg  = (id & 127) << 2;                   // x0 of the float4
    const int y   = id >> 7;

    const unsigned plane = (unsigned)Ydim * Xdim;
    const unsigned pix   = (unsigned)y * Xdim + xg;
    const float* ip = img + pix;
    float* pp = out + pix;
    float* rp = out + (unsigned)Zdim * plane + pix;

    const bool hn = (y > 0);
    const bool hw = (xg > 0);
    const bool l0 = (threadIdx.x & 63) == 0;           // wave lane 0

    F4 h[Pdim];                                        // spectral history ring
#pragma unroll
    for (int p = 0; p < Pdim; ++p) h[p] = F4{{0, 0, 0, 0}};

    F4 cb[3], nb[3];                                   // rotating load buffers
    float wb[3], qb[3];                                // lane-0 edge values

    auto LOAD = [&](int z, int b) {
        const float* p0 = ip + (unsigned)z * plane;
        cb[b] = ld4(p0);
        nb[b] = hn ? ld4(p0 - Xdim) : F4{{0, 0, 0, 0}};
        wb[b] = (l0 && hw)       ? p0[-1]        : 0.0f;   // 1 active lane
        qb[b] = (l0 && hw && hn) ? p0[-Xdim - 1] : 0.0f;   // 1 active lane
    };

    auto STEP = [&](int z, int b) {
        const float* wz = wts + z * NWt;               // uniform addr -> s_load
        const float w3 = wz[3] * (1.0f / 3.0f);
        const float a0 = wz[0] + w3, a1 = wz[1] + w3, a2 = wz[2] + w3;
        float we = __shfl_up(cb[b].v[3], 1);
        float qw = __shfl_up(nb[b].v[3], 1);
        if (l0) { we = wb[b]; qw = qb[b]; }
        f4 pv, rv;
#pragma unroll
        for (int e = 0; e < 4; ++e) {
            const float vn = nb[b].v[e];
            float a = wz[4] * h[0].v[e];
#pragma unroll
            for (int p = 1; p < Pdim; ++p) a = fmaf(wz[4 + p], h[p].v[e], a);
            a = fmaf(a0, vn, a);
            a = fmaf(a1, e ? cb[b].v[e - 1] : we, a);
            a = fmaf(a2, e ? nb[b].v[e - 1] : qw, a);
            a = fminf(fmaxf(a, -32768.0f), 32767.0f);
            pv[e] = a;
            rv[e] = cb[b].v[e] - a;
        }
        __builtin_nontemporal_store(pv, (f4*)(pp + (unsigned)z * plane));
        __builtin_nontemporal_store(rv, (f4*)(rp + (unsigned)z * plane));
#pragma unroll
        for (int p = 0; p < Pdim - 1; ++p) h[p] = h[p + 1];
        h[Pdim - 1] = cb[b];
    };

    LOAD(0, 0);
    LOAD(1, 1);
#pragma unroll 15
    for (int i = 0; i < 120; ++i) {                    // 120 = 8*15, fully static
        LOAD(i + 2, (i + 2) % 3);                      // distance-2 prefetch
        STEP(i, i % 3);
    }
    // pipeline remainder, constant indices (avoid dynamic %3 -> scratch)
    LOAD(122, 2); STEP(120, 0);
    LOAD(123, 0); STEP(121, 1);
    LOAD(124, 1); STEP(122, 2);
    LOAD(125, 2); STEP(123, 0);
    LOAD(126, 0); STEP(124, 1);
    LOAD(127, 1); STEP(125, 2);
    STEP(126, 0);
    STEP(127, 1);
}

extern "C" void kernel_launch(void* const* d_in, const int* in_sizes, int n_in,
                              void* d_out, int out_size, void* d_ws, size_t ws_size,
                              hipStream_t stream) {
    const float* img = (const float*)d_in[0];
    const float* wts = (const float*)d_in[1];
    float* out = (float*)d_out;

    spec_pred_kernel<<<256, 256, 0, stream>>>(img, wts, out);
}

// Round 8
// 69.390 us; speedup vs baseline: 1.1092x; 1.1092x over previous
//
#include <hip/hip_runtime.h>

#define Zdim 128
#define Ydim 512
#define Xdim 512
#define Pdim 15
#define NWt  19
#define CHUNK 64          // z-planes per block; 2 chunks -> only ONE history-preload boundary

typedef __attribute__((ext_vector_type(4))) float f4;
struct F4 { float v[4]; };

__device__ __forceinline__ F4 ld4(const float* p) {
    f4 t = *(const f4*)p;
    F4 r; r.v[0] = t[0]; r.v[1] = t[1]; r.v[2] = t[2]; r.v[3] = t[3];
    return r;
}

// MEASURED-BEST (R6, 68.7 us): one thread per 4 consecutive x, CHUNK=64.
// Design space is bracketed by measurement:
//  - float2 loads (R4): regressed -> issue width per byte is binding, keep f4
//  - CHUNK=128 / 1 wave/SIMD (R7): regressed -> need >=2 waves/SIMD of TLP
//  - CHUNK=64 / 2 waves/SIMD: optimum of preload-traffic vs occupancy
// Structure:
//  - 15-deep register history ring, fully static (60 iters = 4*15, 15%3==0 so
//    ring shifts + the 3 rotating prefetch buffers cost zero movs; remainder
//    iterations written out with constant indices -> nothing dynamic)
//  - weights via wave-uniform global reads -> s_load into SGPRs (no LDS)
//  - west/nw via __shfl_up of lane-1's vectors; lane 0 keeps 1-lane masked loads
//  - distance-2 prefetch, nontemporal f4 stores
//  - XCD-aware remap: bid%8 == XCD; each XCD owns contiguous y -> north-halo
//    reads hit the local L2
__global__ __launch_bounds__(256, 2) void spec_pred_kernel(
    const float* __restrict__ img,
    const float* __restrict__ wts,
    float* __restrict__ out)
{
    const int bid = blockIdx.x;
    const int zc  = bid >> 8;                          // 0..1
    const int r8  = bid & 255;
    const int yb  = ((r8 & 7) << 5) | (r8 >> 3);       // XCD-contiguous y-pair
    const int id  = (yb << 8) | threadIdx.x;           // 0..65535
    const int xg  = (id & 127) << 2;                   // x0 of the float4
    const int y   = id >> 7;

    const unsigned plane = (unsigned)Ydim * Xdim;
    const unsigned pix   = (unsigned)y * Xdim + xg;
    const float* ip = img + pix;
    float* pp = out + pix;
    float* rp = out + (unsigned)Zdim * plane + pix;

    const int  z0 = zc * CHUNK;
    const bool hn = (y > 0);
    const bool hw = (xg > 0);
    const bool l0 = (threadIdx.x & 63) == 0;           // wave lane 0

    F4 h[Pdim];                                        // spectral history ring
    if (z0 == 0) {
#pragma unroll
        for (int p = 0; p < Pdim; ++p) h[p] = F4{{0, 0, 0, 0}};
    } else {
#pragma unroll
        for (int p = 0; p < Pdim; ++p)
            h[p] = ld4(ip + (unsigned)(z0 - Pdim + p) * plane);
    }

    F4 cb[3], nb[3];                                   // rotating load buffers
    float wb[3], qb[3];                                // lane-0 edge values

    auto LOAD = [&](int z, int b) {
        const float* p0 = ip + (unsigned)z * plane;
        cb[b] = ld4(p0);
        nb[b] = hn ? ld4(p0 - Xdim) : F4{{0, 0, 0, 0}};
        wb[b] = (l0 && hw)       ? p0[-1]        : 0.0f;   // 1 active lane
        qb[b] = (l0 && hw && hn) ? p0[-Xdim - 1] : 0.0f;   // 1 active lane
    };

    auto STEP = [&](int z, int b) {
        const float* wz = wts + z * NWt;               // uniform addr -> s_load
        const float w3 = wz[3] * (1.0f / 3.0f);
        const float a0 = wz[0] + w3, a1 = wz[1] + w3, a2 = wz[2] + w3;
        float we = __shfl_up(cb[b].v[3], 1);
        float qw = __shfl_up(nb[b].v[3], 1);
        if (l0) { we = wb[b]; qw = qb[b]; }
        f4 pv, rv;
#pragma unroll
        for (int e = 0; e < 4; ++e) {
            const float vn = nb[b].v[e];
            float a = wz[4] * h[0].v[e];
#pragma unroll
            for (int p = 1; p < Pdim; ++p) a = fmaf(wz[4 + p], h[p].v[e], a);
            a = fmaf(a0, vn, a);
            a = fmaf(a1, e ? cb[b].v[e - 1] : we, a);
            a = fmaf(a2, e ? nb[b].v[e - 1] : qw, a);
            a = fminf(fmaxf(a, -32768.0f), 32767.0f);
            pv[e] = a;
            rv[e] = cb[b].v[e] - a;
        }
        __builtin_nontemporal_store(pv, (f4*)(pp + (unsigned)z * plane));
        __builtin_nontemporal_store(rv, (f4*)(rp + (unsigned)z * plane));
#pragma unroll
        for (int p = 0; p < Pdim - 1; ++p) h[p] = h[p + 1];
        h[Pdim - 1] = cb[b];
    };

    LOAD(z0 + 0, 0);
    LOAD(z0 + 1, 1);
#pragma unroll 15
    for (int i = 0; i < 60; ++i) {                     // 60 = 4*15, fully static
        LOAD(z0 + i + 2, (i + 2) % 3);                 // distance-2 prefetch
        STEP(z0 + i, i % 3);
    }
    // remainder iterations, constant indices (avoid dynamic %3 -> scratch)
    LOAD(z0 + 62, 2); STEP(z0 + 60, 0);
    LOAD(z0 + 63, 0); STEP(z0 + 61, 1);
    STEP(z0 + 62, 2);
    STEP(z0 + 63, 0);
}

extern "C" void kernel_launch(void* const* d_in, const int* in_sizes, int n_in,
                              void* d_out, int out_size, void* d_ws, size_t ws_size,
                              hipStream_t stream) {
    const float* img = (const float*)d_in[0];
    const float* wts = (const float*)d_in[1];
    float* out = (float*)d_out;

    const int grid = 256 * (Zdim / CHUNK);   // 512 blocks of 256 threads
    spec_pred_kernel<<<grid, 256, 0, stream>>>(img, wts, out);
}